// Round 14
// baseline (171.455 us; speedup 1.0000x reference)
//
#include <hip/hip_runtime.h>
#include <math.h>

// DCCA loss: H1,H2 (m=2048, n=64, k=128) fp32.
// gram: TWO-JOB wave-private split (1.75x traffic), ONE TILE PER WAVE (4096 waves
//       -> 16/CU available; r13's 2048 was MLP-starved). No barriers in the main
//       loop; per-block LDS-atomic combine of the 2 tile-slots, then slab dump.
//         jA = S11 quads + S12 col-0 (reads H1B0,H1B1,H2B0)
//         jB = S22 quads + S12 col-1 (reads H2B0,H2B1,H1B0,H1B1)
//       5 f32x16 acc/wave (80 AGPR, unified file; r13 measured 76 arch VGPR, no spill).
// reduce: 160x1024 tree-reduce of 1024 partial slabs into sig.
// solve: MFMA Newton inverse (2 iters), corr^2 = <X1, S12 X2 S12^T>, -sqrt.
#define GRID1 1024             // gram blocks (2 tiles each) / partial slabs

// c = (1 - 1/m)^2 / (m*(m-1)) = 2047 / 2048^3
#define CSCALE 2.3830240e-7f
#define RIDGE 1e-4f

typedef __bf16 bf16x8 __attribute__((ext_vector_type(8)));
typedef float f32x16 __attribute__((ext_vector_type(16)));

#define MFMA32(A, B, C) __builtin_amdgcn_mfma_f32_32x32x16_bf16(A, B, C, 0, 0, 0)

// global quad id q -> (matrix, row-block, col-block); q0..2 S11, 3..5 S22, 6..9 S12
__device__ __constant__ int kMat[10] = {0,0,0, 1,1,1, 2,2,2,2};
__device__ __constant__ int kQi [10] = {0,1,1, 0,1,1, 0,0,1,1};
__device__ __constant__ int kQj [10] = {0,0,1, 0,0,1, 0,1,0,1};

#define CVT8(a, b, hi, lo) do {                                   \
    float fv[8] = {a.x, a.y, a.z, a.w, b.x, b.y, b.z, b.w};       \
    _Pragma("unroll")                                             \
    for (int j = 0; j < 8; ++j) {                                 \
        __bf16 h = (__bf16)fv[j];                                 \
        hi[j] = h;                                                \
        lo[j] = (__bf16)(fv[j] - (float)h);                       \
    }                                                             \
} while (0)

// 256 threads = 4 waves = 2 tile-slots x {jA, jB}; slot s owns tile blockIdx*2+s.
template <bool PARTIALS>
__global__ __launch_bounds__(256, 2) void gram_kernel(const float* __restrict__ H1,
                                                      const float* __restrict__ H2,
                                                      float* __restrict__ sig,
                                                      float* __restrict__ part) {
    __shared__ float red[10240];
    const int tid = threadIdx.x;
    const int w = tid >> 6;
    const int slot = w >> 1;      // tile slot 0/1
    const int job = w & 1;        // 0 = jA, 1 = jB
    const int lane = tid & 63;
    const int l31 = lane & 31;
    const int lhi = lane >> 5;

    // Zero the combine buffer up front; single pre-loop barrier.
    for (int i = tid; i < 10240; i += 256) red[i] = 0.0f;
    __syncthreads();

    f32x16 a0 = {}, a1 = {}, a2 = {}, a3 = {}, a4 = {};

    const size_t tb = (size_t)(blockIdx.x * 2 + slot) * 8192 + (size_t)l31 * 128 + lhi * 8;
    if (job == 0) {
        // jA: S11(0,0)->a0, S11(1,0)->a1, S11(1,1)->a2, S12(0,0)->a3, S12(1,0)->a4
        const float* __restrict__ p = H1 + tb;    // rows l31 / 32+l31
        const float* __restrict__ q = H2 + tb;    // row l31 (block 0 only)
        #pragma unroll 2
        for (int kt = 0; kt < 8; ++kt) {
            const int off = kt * 16;
            float4 uA = *(const float4*)(p + off);
            float4 uB = *(const float4*)(p + off + 4);
            float4 vA = *(const float4*)(p + 4096 + off);
            float4 vB = *(const float4*)(p + 4096 + off + 4);
            float4 qA = *(const float4*)(q + off);
            float4 qB = *(const float4*)(q + off + 4);
            bf16x8 h1a, l1a, h1b, l1b, h2a, l2a;
            CVT8(uA, uB, h1a, l1a);
            CVT8(vA, vB, h1b, l1b);
            CVT8(qA, qB, h2a, l2a);
            a0 = MFMA32(h1a, h1a, a0); a0 = MFMA32(h1a, l1a, a0); a0 = MFMA32(l1a, h1a, a0);
            a1 = MFMA32(h1b, h1a, a1); a1 = MFMA32(h1b, l1a, a1); a1 = MFMA32(l1b, h1a, a1);
            a2 = MFMA32(h1b, h1b, a2); a2 = MFMA32(h1b, l1b, a2); a2 = MFMA32(l1b, h1b, a2);
            a3 = MFMA32(h1a, h2a, a3); a3 = MFMA32(h1a, l2a, a3); a3 = MFMA32(l1a, h2a, a3);
            a4 = MFMA32(h1b, h2a, a4); a4 = MFMA32(h1b, l2a, a4); a4 = MFMA32(l1b, h2a, a4);
        }
    } else {
        // jB: S22(0,0)->a0, S22(1,0)->a1, S22(1,1)->a2, S12(0,1)->a3, S12(1,1)->a4
        const float* __restrict__ p = H2 + tb;    // rows l31 / 32+l31
        const float* __restrict__ q = H1 + tb;    // rows l31 / 32+l31 (S12 A-side)
        #pragma unroll 2
        for (int kt = 0; kt < 8; ++kt) {
            const int off = kt * 16;
            float4 uA = *(const float4*)(p + off);
            float4 uB = *(const float4*)(p + off + 4);
            float4 vA = *(const float4*)(p + 4096 + off);
            float4 vB = *(const float4*)(p + 4096 + off + 4);
            float4 rA = *(const float4*)(q + off);
            float4 rB = *(const float4*)(q + off + 4);
            float4 sA = *(const float4*)(q + 4096 + off);
            float4 sB = *(const float4*)(q + 4096 + off + 4);
            bf16x8 h2a, l2a, h2b, l2b, h1a, l1a, h1b, l1b;
            CVT8(uA, uB, h2a, l2a);
            CVT8(vA, vB, h2b, l2b);
            CVT8(rA, rB, h1a, l1a);
            CVT8(sA, sB, h1b, l1b);
            a0 = MFMA32(h2a, h2a, a0); a0 = MFMA32(h2a, l2a, a0); a0 = MFMA32(l2a, h2a, a0);
            a1 = MFMA32(h2b, h2a, a1); a1 = MFMA32(h2b, l2a, a1); a1 = MFMA32(l2b, h2a, a1);
            a2 = MFMA32(h2b, h2b, a2); a2 = MFMA32(h2b, l2b, a2); a2 = MFMA32(l2b, h2b, a2);
            a3 = MFMA32(h1a, h2b, a3); a3 = MFMA32(h1a, l2b, a3); a3 = MFMA32(l1a, h2b, a3);
            a4 = MFMA32(h1b, h2b, a4); a4 = MFMA32(h1b, l2b, a4); a4 = MFMA32(l1b, h2b, a4);
        }
    }

    // Combine the 2 slots via LDS atomics (quads within a slot are wave-disjoint,
    // across slots they collide -> atomic). Barriers only here, not in the loop.
    // C/D 32x32 layout: col = lane&31, row = (rg&3)+8*(rg>>2)+4*(lane>>5)
#define PUTQ(q, acc)                                                       \
    _Pragma("unroll")                                                      \
    for (int rg = 0; rg < 16; ++rg) {                                      \
        int row = (rg & 3) + 8 * (rg >> 2) + 4 * lhi;                      \
        atomicAdd(&red[(q) * 1024 + row * 32 + l31], acc[rg]);             \
    }
    if (job == 0) { PUTQ(0, a0) PUTQ(1, a1) PUTQ(2, a2) PUTQ(6, a3) PUTQ(8, a4) }
    else          { PUTQ(3, a0) PUTQ(4, a1) PUTQ(5, a2) PUTQ(7, a3) PUTQ(9, a4) }
#undef PUTQ
    __syncthreads();

    if (PARTIALS) {
        float* dst = part + (size_t)blockIdx.x * 10240;
        for (int i = tid; i < 2560; i += 256)
            ((float4*)dst)[i] = ((const float4*)red)[i];
    } else {
        #pragma unroll
        for (int q = 0; q < 10; ++q) {
            for (int jx = tid; jx < 1024; jx += 256) {
                int r = jx >> 5, c = jx & 31;
                atomicAdd(&sig[kMat[q] * 4096 + (kQi[q] * 32 + r) * 64 + kQj[q] * 32 + c],
                          red[q * 1024 + jx]);
            }
        }
    }
}

// 160 blocks x 1024 threads: block owns 64 partial-space slots; wave w of 16 sums
// slabs {w, w+16, ...}; cross-wave combine in LDS; scatter into sig.
__global__ __launch_bounds__(1024) void reduce_kernel(const float* __restrict__ part,
                                                      float* __restrict__ sig) {
    __shared__ float buf[16][64];
    const int tid = threadIdx.x;
    const int w = tid >> 6;
    const int lane = tid & 63;
    const int o0 = blockIdx.x * 64;

    float s = 0.0f;
    for (int p = w; p < GRID1; p += 16)
        s += part[(size_t)p * 10240 + o0 + lane];
    buf[w][lane] = s;
    __syncthreads();

    if (w == 0) {
        float v = 0.0f;
        #pragma unroll
        for (int i = 0; i < 16; ++i) v += buf[i][lane];
        int o = o0 + lane;
        int q = o >> 10, idx = o & 1023;
        int r = idx >> 5, c = idx & 31;
        sig[kMat[q] * 4096 + (kQi[q] * 32 + r) * 64 + kQj[q] * 32 + c] = v;
    }
}

// One block, 512 threads (8 waves). Newton inverse on MFMA:
//   X0 = (64/tr A) I;  X <- 2X - X*A*X  (2 iters; residual ~2.6e-6)
//   corr^2 = <X1, S12*X2*S12^T>  transpose-free via mfma(A,B)=A*B^T + symmetry.
#define SST 72
#define SPL (64 * SST)
// plane ids: 0/1 A1 h/l, 2/3 A2 h/l, 4/5 X1 h/l, 6/7 X2 h/l, 8/9 W1|S12 h/l, 10/11 W2|Z h/l

__global__ __launch_bounds__(512, 1) void solve_kernel(const float* __restrict__ sig,
                                                       float* __restrict__ out) {
    __shared__ __attribute__((aligned(16))) __bf16 pl[12 * SPL];
    __shared__ float ainv[2];
    __shared__ float rbuf[4];
    const int tid = threadIdx.x;
    const int w = tid >> 6, lane = tid & 63, l31 = lane & 31, lhi = lane >> 5;
    const int g = w >> 2;          // matrix group: 0 -> S11, 1 -> S22
    const int qw = w & 3, qi = qw >> 1, qj = qw & 1;
    const int ra = qi * 32 + l31;  // A-operand fragment row
    const int rb = qj * 32 + l31;  // B-operand fragment row

    // Load A = CSCALE*Gram + ridge, symmetric reconstruct (sig quad (0,1) is zeros).
    for (int idx = tid; idx < 4096; idx += 512) {
        int r = idx >> 6, c = idx & 63;
        int src = (r < 32 && c >= 32) ? (c * 64 + r) : idx;
        float rg = (r == c) ? RIDGE : 0.0f;
        float v1 = CSCALE * sig[src] + rg;
        float v2 = CSCALE * sig[4096 + src] + rg;
        __bf16 h1 = (__bf16)v1, h2 = (__bf16)v2;
        pl[0 * SPL + r * SST + c] = h1;
        pl[1 * SPL + r * SST + c] = (__bf16)(v1 - (float)h1);
        pl[2 * SPL + r * SST + c] = h2;
        pl[3 * SPL + r * SST + c] = (__bf16)(v2 - (float)h2);
    }
    if (w == 0 || w == 4) {        // alpha_inv = 64 / tr(A)
        int mg = (w == 4);
        float d = CSCALE * sig[mg * 4096 + lane * 65] + RIDGE;
        #pragma unroll
        for (int off = 32; off; off >>= 1) d += __shfl_xor(d, off, 64);
        if (lane == 0) ainv[mg] = 64.0f / d;
    }
    __syncthreads();

    // X0 = ainv * I
    for (int idx = tid; idx < 4096; idx += 512) {
        int r = idx >> 6, c = idx & 63;
        float v1 = (r == c) ? ainv[0] : 0.0f;
        float v2 = (r == c) ? ainv[1] : 0.0f;
        __bf16 h1 = (__bf16)v1, h2 = (__bf16)v2;
        pl[4 * SPL + r * SST + c] = h1;
        pl[5 * SPL + r * SST + c] = (__bf16)(v1 - (float)h1);
        pl[6 * SPL + r * SST + c] = h2;
        pl[7 * SPL + r * SST + c] = (__bf16)(v2 - (float)h2);
    }
    __syncthreads();

    for (int it = 0; it < 2; ++it) {
        // W = X * A
        f32x16 accw = {};
        #pragma unroll
        for (int ks = 0; ks < 4; ++ks) {
            int col = ks * 16 + lhi * 8;
            bf16x8 xh = *(const bf16x8*)&pl[(4 + 2 * g) * SPL + ra * SST + col];
            bf16x8 xl = *(const bf16x8*)&pl[(5 + 2 * g) * SPL + ra * SST + col];
            bf16x8 ah = *(const bf16x8*)&pl[(0 + 2 * g) * SPL + rb * SST + col];
            bf16x8 al = *(const bf16x8*)&pl[(1 + 2 * g) * SPL + rb * SST + col];
            accw = MFMA32(xh, ah, accw);
            accw = MFMA32(xh, al, accw);
            accw = MFMA32(xl, ah, accw);
        }
        #pragma unroll
        for (int rg = 0; rg < 16; ++rg) {
            int row = qi * 32 + (rg & 3) + 8 * (rg >> 2) + 4 * lhi;
            int col = qj * 32 + l31;
            float v = accw[rg];
            __bf16 h = (__bf16)v;
            pl[(8 + 2 * g) * SPL + row * SST + col] = h;
            pl[(9 + 2 * g) * SPL + row * SST + col] = (__bf16)(v - (float)h);
        }
        __syncthreads();

        // S = W * X ; X <- 2X - S
        f32x16 accs = {};
        #pragma unroll
        for (int ks = 0; ks < 4; ++ks) {
            int col = ks * 16 + lhi * 8;
            bf16x8 wh = *(const bf16x8*)&pl[(8 + 2 * g) * SPL + ra * SST + col];
            bf16x8 wl = *(const bf16x8*)&pl[(9 + 2 * g) * SPL + ra * SST + col];
            bf16x8 xh = *(const bf16x8*)&pl[(4 + 2 * g) * SPL + rb * SST + col];
            bf16x8 xl = *(const bf16x8*)&pl[(5 + 2 * g) * SPL + rb * SST + col];
            accs = MFMA32(wh, xh, accs);
            accs = MFMA32(wh, xl, accs);
            accs = MFMA32(wl, xh, accs);
        }
        __syncthreads();   // all X reads done before X writes
        #pragma unroll
        for (int rg = 0; rg < 16; ++rg) {
            int row = qi * 32 + (rg & 3) + 8 * (rg >> 2) + 4 * lhi;
            int col = qj * 32 + l31;
            float xv = (float)pl[(4 + 2 * g) * SPL + row * SST + col]
                     + (float)pl[(5 + 2 * g) * SPL + row * SST + col];
            float nv = 2.0f * xv - accs[rg];
            __bf16 h = (__bf16)nv;
            pl[(4 + 2 * g) * SPL + row * SST + col] = h;
            pl[(5 + 2 * g) * SPL + row * SST + col] = (__bf16)(nv - (float)h);
        }
        __syncthreads();
    }

    // S12 -> planes 8/9
    for (int idx = tid; idx < 4096; idx += 512) {
        int r = idx >> 6, c = idx & 63;
        float v = CSCALE * sig[8192 + idx];
        __bf16 h = (__bf16)v;
        pl[8 * SPL + r * SST + c] = h;
        pl[9 * SPL + r * SST + c] = (__bf16)(v - (float)h);
    }
    __syncthreads();

    // Z = S12 * X2 -> planes 10/11 (group 1)
    if (g == 1) {
        f32x16 accz = {};
        #pragma unroll
        for (int ks = 0; ks < 4; ++ks) {
            int col = ks * 16 + lhi * 8;
            bf16x8 sh = *(const bf16x8*)&pl[8 * SPL + ra * SST + col];
            bf16x8 sl = *(const bf16x8*)&pl[9 * SPL + ra * SST + col];
            bf16x8 xh = *(const bf16x8*)&pl[6 * SPL + rb * SST + col];
            bf16x8 xl = *(const bf16x8*)&pl[7 * SPL + rb * SST + col];
            accz = MFMA32(sh, xh, accz);
            accz = MFMA32(sh, xl, accz);
            accz = MFMA32(sl, xh, accz);
        }
        #pragma unroll
        for (int rg = 0; rg < 16; ++rg) {
            int row = qi * 32 + (rg & 3) + 8 * (rg >> 2) + 4 * lhi;
            int col = qj * 32 + l31;
            float v = accz[rg];
            __bf16 h = (__bf16)v;
            pl[10 * SPL + row * SST + col] = h;
            pl[11 * SPL + row * SST + col] = (__bf16)(v - (float)h);
        }
    }
    __syncthreads();

    // M = Z * S12^T (group 0); corr^2 += M .* X1
    if (g == 0) {
        f32x16 accm = {};
        #pragma unroll
        for (int ks = 0; ks < 4; ++ks) {
            int col = ks * 16 + lhi * 8;
            bf16x8 zh = *(const bf16x8*)&pl[10 * SPL + ra * SST + col];
            bf16x8 zl = *(const bf16x8*)&pl[11 * SPL + ra * SST + col];
            bf16x8 sh = *(const bf16x8*)&pl[8 * SPL + rb * SST + col];
            bf16x8 sl = *(const bf16x8*)&pl[9 * SPL + rb * SST + col];
            accm = MFMA32(zh, sh, accm);
            accm = MFMA32(zh, sl, accm);
            accm = MFMA32(zl, sh, accm);
        }
        float p = 0.0f;
        #pragma unroll
        for (int rg = 0; rg < 16; ++rg) {
            int row = qi * 32 + (rg & 3) + 8 * (rg >> 2) + 4 * lhi;
            int col = qj * 32 + l31;
            float x1v = (float)pl[4 * SPL + row * SST + col]
                      + (float)pl[5 * SPL + row * SST + col];
            p += accm[rg] * x1v;
        }
        #pragma unroll
        for (int off = 32; off; off >>= 1) p += __shfl_xor(p, off, 64);
        if (lane == 0) rbuf[qw] = p;
    }
    __syncthreads();
    if (tid == 0) out[0] = -sqrtf(rbuf[0] + rbuf[1] + rbuf[2] + rbuf[3]);
}

extern "C" void kernel_launch(void* const* d_in, const int* in_sizes, int n_in,
                              void* d_out, int out_size, void* d_ws, size_t ws_size,
                              hipStream_t stream) {
    const float* H1 = (const float*)d_in[0];
    const float* H2 = (const float*)d_in[1];
    float* sig = (float*)d_ws;                      // 12288 floats = 48 KB
    float* part = (float*)((char*)d_ws + 49152);    // 1024 * 10240 floats = 40 MB
    const size_t need = 49152 + (size_t)GRID1 * 10240 * 4;

    if (ws_size >= need) {
        // No memset needed: reduce_kernel overwrites every sig slot solve reads.
        gram_kernel<true><<<GRID1, 256, 0, stream>>>(H1, H2, sig, part);
        reduce_kernel<<<160, 1024, 0, stream>>>(part, sig);
    } else {
        hipMemsetAsync(d_ws, 0, 49152, stream);
        gram_kernel<false><<<GRID1, 256, 0, stream>>>(H1, H2, sig, nullptr);
    }
    solve_kernel<<<1, 512, 0, stream>>>(sig, (float*)d_out);
}

// Round 15
// 54.209 us; speedup vs baseline: 3.1629x; 3.1629x over previous
//
#include <hip/hip_runtime.h>
#include <math.h>

// DCCA loss: H1,H2 (m=2048, n=64, k=128) fp32.
// BEST-MEASURED CONFIG (consolidation round):
// gram: r4/r5 structure verbatim -- TPB=4, full-K LDS staging (69.6KB, RSU=136,
//       0 conflicts measured), 4 job-split waves, non-atomic slab dump. 50.2us measured.
// reduce: 160x1024 tree-reduce of 512 slabs (20MB).
// solve: MFMA Newton inverse, 2 iters (validated r13/r14), corr^2 = <X1,S12 X2 S12^T>.
#define TPB 4
#define GRID1 512              // gram blocks / partial slabs
#define RSU 136                // LDS row stride in bf16 (272B; 0 conflicts measured r5)
#define PLANE (64 * RSU)

// c = (1 - 1/m)^2 / (m*(m-1)) = 2047 / 2048^3
#define CSCALE 2.3830240e-7f
#define RIDGE 1e-4f

typedef __bf16 bf16x8 __attribute__((ext_vector_type(8)));
typedef float f32x16 __attribute__((ext_vector_type(16)));

#define MFMA32(A, B, C) __builtin_amdgcn_mfma_f32_32x32x16_bf16(A, B, C, 0, 0, 0)

// global quad id q -> (matrix, row-block, col-block); q0..2 S11, 3..5 S22, 6..9 S12
__device__ __constant__ int kMat[10] = {0,0,0, 1,1,1, 2,2,2,2};
__device__ __constant__ int kQi [10] = {0,1,1, 0,1,1, 0,0,1,1};
__device__ __constant__ int kQj [10] = {0,0,1, 0,0,1, 0,1,0,1};

template <bool PARTIALS>
__global__ __launch_bounds__(256, 2) void gram_kernel(const float* __restrict__ H1,
                                                      const float* __restrict__ H2,
                                                      float* __restrict__ sig,
                                                      float* __restrict__ part) {
    __shared__ __bf16 lds[4 * PLANE];   // planes: 0=H1hi 1=H1lo 2=H2hi 3=H2lo (69632 B)
    const int tid = threadIdx.x;
    const int w = tid >> 6;
    const int lane = tid & 63;
    const int l31 = lane & 31;
    const int lhi = lane >> 5;

    // wave job: w0 -> S11 quads (0,0),(1,0),(1,1); w1 -> S22 same;
    //           w2 -> S12 rows 0-31; w3 -> S12 rows 32-63
    f32x16 a0 = {}, a1 = {}, a2 = {};

    for (int t = 0; t < TPB; ++t) {
        const size_t base = (size_t)(blockIdx.x * TPB + t) * (64 * 128);
        __syncthreads();  // protect LDS vs previous tile's readers
        #pragma unroll
        for (int v = 0; v < 2; ++v) {
            const float* __restrict__ Hsrc = (v ? H2 : H1) + base;
            __bf16* ph = lds + 2 * v * PLANE;
            __bf16* pllo = ph + PLANE;
            #pragma unroll
            for (int it = 0; it < 4; ++it) {
                int chunk = it * 256 + tid;          // 1024 chunks of 8 floats
                int r = chunk >> 4, c8 = chunk & 15;
                const float* src = Hsrc + r * 128 + c8 * 8;
                float4 u0 = *(const float4*)src;
                float4 u1 = *(const float4*)(src + 4);
                float fv[8] = {u0.x, u0.y, u0.z, u0.w, u1.x, u1.y, u1.z, u1.w};
                bf16x8 hi, lo;
                #pragma unroll
                for (int j = 0; j < 8; ++j) {
                    __bf16 h = (__bf16)fv[j];
                    hi[j] = h;
                    lo[j] = (__bf16)(fv[j] - (float)h);
                }
                *(bf16x8*)&ph[r * RSU + c8 * 8] = hi;
                *(bf16x8*)&pllo[r * RSU + c8 * 8] = lo;
            }
        }
        __syncthreads();

        if (w < 2) {
            const __bf16* ph = lds + 2 * w * PLANE;
            const __bf16* pllo = ph + PLANE;
            #pragma unroll
            for (int kt = 0; kt < 8; ++kt) {
                const int col = kt * 16 + lhi * 8;
                bf16x8 h0 = *(const bf16x8*)&ph[l31 * RSU + col];
                bf16x8 h1 = *(const bf16x8*)&ph[(32 + l31) * RSU + col];
                bf16x8 l0 = *(const bf16x8*)&pllo[l31 * RSU + col];
                bf16x8 l1 = *(const bf16x8*)&pllo[(32 + l31) * RSU + col];
                a0 = MFMA32(h0, h0, a0); a0 = MFMA32(h0, l0, a0); a0 = MFMA32(l0, h0, a0);
                a1 = MFMA32(h1, h0, a1); a1 = MFMA32(h1, l0, a1); a1 = MFMA32(l1, h0, a1);
                a2 = MFMA32(h1, h1, a2); a2 = MFMA32(h1, l1, a2); a2 = MFMA32(l1, h1, a2);
            }
        } else {
            const int arow = ((w == 3) ? 32 : 0) + l31;
            #pragma unroll
            for (int kt = 0; kt < 8; ++kt) {
                const int col = kt * 16 + lhi * 8;
                bf16x8 Ahf = *(const bf16x8*)&lds[0 * PLANE + arow * RSU + col];
                bf16x8 Alf = *(const bf16x8*)&lds[1 * PLANE + arow * RSU + col];
                bf16x8 B0h = *(const bf16x8*)&lds[2 * PLANE + l31 * RSU + col];
                bf16x8 B0l = *(const bf16x8*)&lds[3 * PLANE + l31 * RSU + col];
                bf16x8 B1h = *(const bf16x8*)&lds[2 * PLANE + (32 + l31) * RSU + col];
                bf16x8 B1l = *(const bf16x8*)&lds[3 * PLANE + (32 + l31) * RSU + col];
                a0 = MFMA32(Ahf, B0h, a0); a0 = MFMA32(Ahf, B0l, a0); a0 = MFMA32(Alf, B0h, a0);
                a1 = MFMA32(Ahf, B1h, a1); a1 = MFMA32(Ahf, B1l, a1); a1 = MFMA32(Alf, B1h, a1);
            }
        }
    }

    // Flush: quads are wave-disjoint -> non-atomic partial dump (or atomic fallback).
    const int q0 = (w == 0) ? 0 : (w == 1) ? 3 : (w == 2) ? 6 : 8;
    const int nq = (w < 2) ? 3 : 2;
    f32x16 A[3] = {a0, a1, a2};
    if (PARTIALS) {
        float* dst = part + (size_t)blockIdx.x * 10240 + q0 * 1024;
        #pragma unroll
        for (int qq = 0; qq < 3; ++qq) {
            if (qq < nq) {
                #pragma unroll
                for (int rg = 0; rg < 16; ++rg) {
                    // C/D 32x32 layout: col = lane&31, row = (rg&3)+8*(rg>>2)+4*(lane>>5)
                    int row = (rg & 3) + 8 * (rg >> 2) + 4 * lhi;
                    dst[qq * 1024 + row * 32 + l31] = A[qq][rg];
                }
            }
        }
    } else {
        #pragma unroll
        for (int qq = 0; qq < 3; ++qq) {
            if (qq < nq) {
                const int q = q0 + qq;
                #pragma unroll
                for (int rg = 0; rg < 16; ++rg) {
                    int row = (rg & 3) + 8 * (rg >> 2) + 4 * lhi;
                    atomicAdd(&sig[kMat[q] * 4096 + (kQi[q] * 32 + row) * 64 + kQj[q] * 32 + l31],
                              A[qq][rg]);
                }
            }
        }
    }
}

// 160 blocks x 1024 threads: block owns 64 partial-space slots; wave w of 16 sums
// slabs {w, w+16, ...} (32-deep chains); cross-wave combine in LDS; scatter into sig.
__global__ __launch_bounds__(1024) void reduce_kernel(const float* __restrict__ part,
                                                      float* __restrict__ sig) {
    __shared__ float buf[16][64];
    const int tid = threadIdx.x;
    const int w = tid >> 6;
    const int lane = tid & 63;
    const int o0 = blockIdx.x * 64;

    float s = 0.0f;
    for (int p = w; p < GRID1; p += 16)
        s += part[(size_t)p * 10240 + o0 + lane];
    buf[w][lane] = s;
    __syncthreads();

    if (w == 0) {
        float v = 0.0f;
        #pragma unroll
        for (int i = 0; i < 16; ++i) v += buf[i][lane];
        int o = o0 + lane;
        int q = o >> 10, idx = o & 1023;
        int r = idx >> 5, c = idx & 31;
        sig[kMat[q] * 4096 + (kQi[q] * 32 + r) * 64 + kQj[q] * 32 + c] = v;
    }
}

// One block, 512 threads (8 waves). Newton inverse on MFMA:
//   X0 = (64/tr A) I;  X <- 2X - X*A*X  (2 iters; residual ~2.6e-6, validated r13/r14)
//   corr^2 = <X1, S12*X2*S12^T>  transpose-free via mfma(A,B)=A*B^T + symmetry.
#define SST 72
#define SPL (64 * SST)
// plane ids: 0/1 A1 h/l, 2/3 A2 h/l, 4/5 X1 h/l, 6/7 X2 h/l, 8/9 W1|S12 h/l, 10/11 W2|Z h/l

__global__ __launch_bounds__(512, 1) void solve_kernel(const float* __restrict__ sig,
                                                       float* __restrict__ out) {
    __shared__ __attribute__((aligned(16))) __bf16 pl[12 * SPL];
    __shared__ float ainv[2];
    __shared__ float rbuf[4];
    const int tid = threadIdx.x;
    const int w = tid >> 6, lane = tid & 63, l31 = lane & 31, lhi = lane >> 5;
    const int g = w >> 2;          // matrix group: 0 -> S11, 1 -> S22
    const int qw = w & 3, qi = qw >> 1, qj = qw & 1;
    const int ra = qi * 32 + l31;  // A-operand fragment row
    const int rb = qj * 32 + l31;  // B-operand fragment row

    // Load A = CSCALE*Gram + ridge, symmetric reconstruct (sig quad (0,1) is zeros).
    for (int idx = tid; idx < 4096; idx += 512) {
        int r = idx >> 6, c = idx & 63;
        int src = (r < 32 && c >= 32) ? (c * 64 + r) : idx;
        float rg = (r == c) ? RIDGE : 0.0f;
        float v1 = CSCALE * sig[src] + rg;
        float v2 = CSCALE * sig[4096 + src] + rg;
        __bf16 h1 = (__bf16)v1, h2 = (__bf16)v2;
        pl[0 * SPL + r * SST + c] = h1;
        pl[1 * SPL + r * SST + c] = (__bf16)(v1 - (float)h1);
        pl[2 * SPL + r * SST + c] = h2;
        pl[3 * SPL + r * SST + c] = (__bf16)(v2 - (float)h2);
    }
    if (w == 0 || w == 4) {        // alpha_inv = 64 / tr(A)
        int mg = (w == 4);
        float d = CSCALE * sig[mg * 4096 + lane * 65] + RIDGE;
        #pragma unroll
        for (int off = 32; off; off >>= 1) d += __shfl_xor(d, off, 64);
        if (lane == 0) ainv[mg] = 64.0f / d;
    }
    __syncthreads();

    // X0 = ainv * I
    for (int idx = tid; idx < 4096; idx += 512) {
        int r = idx >> 6, c = idx & 63;
        float v1 = (r == c) ? ainv[0] : 0.0f;
        float v2 = (r == c) ? ainv[1] : 0.0f;
        __bf16 h1 = (__bf16)v1, h2 = (__bf16)v2;
        pl[4 * SPL + r * SST + c] = h1;
        pl[5 * SPL + r * SST + c] = (__bf16)(v1 - (float)h1);
        pl[6 * SPL + r * SST + c] = h2;
        pl[7 * SPL + r * SST + c] = (__bf16)(v2 - (float)h2);
    }
    __syncthreads();

    for (int it = 0; it < 2; ++it) {
        // W = X * A
        f32x16 accw = {};
        #pragma unroll
        for (int ks = 0; ks < 4; ++ks) {
            int col = ks * 16 + lhi * 8;
            bf16x8 xh = *(const bf16x8*)&pl[(4 + 2 * g) * SPL + ra * SST + col];
            bf16x8 xl = *(const bf16x8*)&pl[(5 + 2 * g) * SPL + ra * SST + col];
            bf16x8 ah = *(const bf16x8*)&pl[(0 + 2 * g) * SPL + rb * SST + col];
            bf16x8 al = *(const bf16x8*)&pl[(1 + 2 * g) * SPL + rb * SST + col];
            accw = MFMA32(xh, ah, accw);
            accw = MFMA32(xh, al, accw);
            accw = MFMA32(xl, ah, accw);
        }
        #pragma unroll
        for (int rg = 0; rg < 16; ++rg) {
            int row = qi * 32 + (rg & 3) + 8 * (rg >> 2) + 4 * lhi;
            int col = qj * 32 + l31;
            float v = accw[rg];
            __bf16 h = (__bf16)v;
            pl[(8 + 2 * g) * SPL + row * SST + col] = h;
            pl[(9 + 2 * g) * SPL + row * SST + col] = (__bf16)(v - (float)h);
        }
        __syncthreads();

        // S = W * X ; X <- 2X - S
        f32x16 accs = {};
        #pragma unroll
        for (int ks = 0; ks < 4; ++ks) {
            int col = ks * 16 + lhi * 8;
            bf16x8 wh = *(const bf16x8*)&pl[(8 + 2 * g) * SPL + ra * SST + col];
            bf16x8 wl = *(const bf16x8*)&pl[(9 + 2 * g) * SPL + ra * SST + col];
            bf16x8 xh = *(const bf16x8*)&pl[(4 + 2 * g) * SPL + rb * SST + col];
            bf16x8 xl = *(const bf16x8*)&pl[(5 + 2 * g) * SPL + rb * SST + col];
            accs = MFMA32(wh, xh, accs);
            accs = MFMA32(wh, xl, accs);
            accs = MFMA32(wl, xh, accs);
        }
        __syncthreads();   // all X reads done before X writes
        #pragma unroll
        for (int rg = 0; rg < 16; ++rg) {
            int row = qi * 32 + (rg & 3) + 8 * (rg >> 2) + 4 * lhi;
            int col = qj * 32 + l31;
            float xv = (float)pl[(4 + 2 * g) * SPL + row * SST + col]
                     + (float)pl[(5 + 2 * g) * SPL + row * SST + col];
            float nv = 2.0f * xv - accs[rg];
            __bf16 h = (__bf16)nv;
            pl[(4 + 2 * g) * SPL + row * SST + col] = h;
            pl[(5 + 2 * g) * SPL + row * SST + col] = (__bf16)(nv - (float)h);
        }
        __syncthreads();
    }

    // S12 -> planes 8/9
    for (int idx = tid; idx < 4096; idx += 512) {
        int r = idx >> 6, c = idx & 63;
        float v = CSCALE * sig[8192 + idx];
        __bf16 h = (__bf16)v;
        pl[8 * SPL + r * SST + c] = h;
        pl[9 * SPL + r * SST + c] = (__bf16)(v - (float)h);
    }
    __syncthreads();

    // Z = S12 * X2 -> planes 10/11 (group 1)
    if (g == 1) {
        f32x16 accz = {};
        #pragma unroll
        for (int ks = 0; ks < 4; ++ks) {
            int col = ks * 16 + lhi * 8;
            bf16x8 sh = *(const bf16x8*)&pl[8 * SPL + ra * SST + col];
            bf16x8 sl = *(const bf16x8*)&pl[9 * SPL + ra * SST + col];
            bf16x8 xh = *(const bf16x8*)&pl[6 * SPL + rb * SST + col];
            bf16x8 xl = *(const bf16x8*)&pl[7 * SPL + rb * SST + col];
            accz = MFMA32(sh, xh, accz);
            accz = MFMA32(sh, xl, accz);
            accz = MFMA32(sl, xh, accz);
        }
        #pragma unroll
        for (int rg = 0; rg < 16; ++rg) {
            int row = qi * 32 + (rg & 3) + 8 * (rg >> 2) + 4 * lhi;
            int col = qj * 32 + l31;
            float v = accz[rg];
            __bf16 h = (__bf16)v;
            pl[10 * SPL + row * SST + col] = h;
            pl[11 * SPL + row * SST + col] = (__bf16)(v - (float)h);
        }
    }
    __syncthreads();

    // M = Z * S12^T (group 0); corr^2 += M .* X1
    if (g == 0) {
        f32x16 accm = {};
        #pragma unroll
        for (int ks = 0; ks < 4; ++ks) {
            int col = ks * 16 + lhi * 8;
            bf16x8 zh = *(const bf16x8*)&pl[10 * SPL + ra * SST + col];
            bf16x8 zl = *(const bf16x8*)&pl[11 * SPL + ra * SST + col];
            bf16x8 sh = *(const bf16x8*)&pl[8 * SPL + rb * SST + col];
            bf16x8 sl = *(const bf16x8*)&pl[9 * SPL + rb * SST + col];
            accm = MFMA32(zh, sh, accm);
            accm = MFMA32(zh, sl, accm);
            accm = MFMA32(zl, sh, accm);
        }
        float p = 0.0f;
        #pragma unroll
        for (int rg = 0; rg < 16; ++rg) {
            int row = qi * 32 + (rg & 3) + 8 * (rg >> 2) + 4 * lhi;
            int col = qj * 32 + l31;
            float x1v = (float)pl[4 * SPL + row * SST + col]
                      + (float)pl[5 * SPL + row * SST + col];
            p += accm[rg] * x1v;
        }
        #pragma unroll
        for (int off = 32; off; off >>= 1) p += __shfl_xor(p, off, 64);
        if (lane == 0) rbuf[qw] = p;
    }
    __syncthreads();
    if (tid == 0) out[0] = -sqrtf(rbuf[0] + rbuf[1] + rbuf[2] + rbuf[3]);
}

extern "C" void kernel_launch(void* const* d_in, const int* in_sizes, int n_in,
                              void* d_out, int out_size, void* d_ws, size_t ws_size,
                              hipStream_t stream) {
    const float* H1 = (const float*)d_in[0];
    const float* H2 = (const float*)d_in[1];
    float* sig = (float*)d_ws;                      // 12288 floats = 48 KB
    float* part = (float*)((char*)d_ws + 49152);    // 512 * 10240 floats = 20 MB
    const size_t need = 49152 + (size_t)GRID1 * 10240 * 4;

    if (ws_size >= need) {
        // No memset needed: reduce_kernel overwrites every sig slot solve reads.
        gram_kernel<true><<<GRID1, 256, 0, stream>>>(H1, H2, sig, part);
        reduce_kernel<<<160, 1024, 0, stream>>>(part, sig);
    } else {
        hipMemsetAsync(d_ws, 0, 49152, stream);
        gram_kernel<false><<<GRID1, 256, 0, stream>>>(H1, H2, sig, nullptr);
    }
    solve_kernel<<<1, 512, 0, stream>>>(sig, (float*)d_out);
}